// Round 7
// baseline (5429.039 us; speedup 1.0000x reference)
//
#include <hip/hip_runtime.h>
#include <math.h>

// ---------------------------------------------------------------------------
// WorldModel RSSM forward losses — R12.
// R11 (bigger tiles) was NEUTRAL -> all GEMMs here are latency-bound, not
// throughput-bound. Budget: Phase B ~1500us (63 steps x 2 kernels, each
// ~8-10us vs ~4-5us latency floor). Root cause: prefetch depth 1 — each
// K-iter exposes (load_latency - compute) ~300-600cy of stall at 1 wave/SIMD
// occupancy. R12: depth-2 register prefetch (pattern proven in R10 stage-1,
// refcheck'd absmax 0; here with NORMAL cached loads) in the 4 hot bodies:
//   step_g (63x), gru_step (63x), gemm_big (27x), decobs_loss (9x).
// Preload iters 0,1 -> regs[0],regs[1]; per iter: write regs[cur]->LDS[cur],
// barrier, reload regs[cur] from k0+2*BK, MFMA from LDS[cur]. One barrier
// per iter; prefetch distance 2 iters covers L2/L3 latency.
// Everything else identical to R11 (passed, absmax 0).
// ---------------------------------------------------------------------------

namespace {

typedef unsigned short ushort;
typedef __attribute__((ext_vector_type(8))) short short8;   // 8 bf16 in 4 VGPRs
typedef __attribute__((ext_vector_type(4))) float f32x4;

constexpr int TSTEPS = 63;
constexpr int NB     = 256;
constexpr int NACT   = 32;
constexpr int NROWS  = TSTEPS * NB;   // 16128
constexpr int TGRP   = 7;
constexpr int NGRP   = 9;
constexpr int GROWS  = TGRP * NB;     // 1792 = 28*64

// ---- workspace layout (floats) --------------------------------------------
constexpr size_t OFF_POSTE = 0;                                     // f32 16128x512
constexpr size_t OFF_OBSB  = OFF_POSTE + (size_t)NROWS * 512;       // (unused)
constexpr size_t OFF_E1C   = OFF_OBSB + (size_t)GROWS * 512 / 2;    // u16 1792x1024
constexpr size_t OFF_EMBC  = OFF_E1C + (size_t)GROWS * 1024 / 2;    // u16 1792x1024
constexpr size_t OFF_FEATC = OFF_EMBC + (size_t)GROWS * 1024 / 2;   // u16 1792x1280
constexpr size_t OFF_DR1C  = OFF_FEATC + (size_t)GROWS * 1280 / 2;  // u16 1792x2048
constexpr size_t OFF_WHT   = OFF_DR1C + (size_t)GROWS * 2048 / 2;   // u16 4096x1024
constexpr size_t OFF_WIHT  = OFF_WHT + (size_t)4096 * 1024 / 2;     // u16 3072x288
constexpr size_t OFF_WDRT  = OFF_WIHT + (size_t)3072 * 288 / 2;     // u16 2048x1280
constexpr size_t OFF_E1T   = OFF_WDRT + (size_t)2048 * 1280 / 2;    // u16 1024x512
constexpr size_t OFF_E2T   = OFF_E1T + (size_t)1024 * 512 / 2;      // u16 1024x1024
constexpr size_t OFF_PET   = OFF_E2T + (size_t)1024 * 1024 / 2;     // u16 512x1024
constexpr size_t OFF_DW2T  = OFF_PET + (size_t)512 * 1024 / 2;      // u16 512x1024
constexpr size_t OFF_BDR   = OFF_DW2T + (size_t)512 * 1024 / 2;     // f32 2048
constexpr size_t OFF_G     = OFF_BDR + 2048;                        // f32 256x3072
constexpr size_t OFF_H     = OFF_G + (size_t)NB * 3072;             // f32 256x1024
constexpr size_t OFF_HB    = OFF_H + (size_t)NB * 1024;             // u16 256x1024
constexpr size_t OFF_ACC   = OFF_HB + (size_t)NB * 1024 / 2;        // f32 16
constexpr size_t OFF_XBUF  = OFF_ACC + 16;                          // u16 256x288

__device__ __forceinline__ ushort f2bf(float f) {
  unsigned int u = __float_as_uint(f);
  unsigned int r = (u + 0x7fffu + ((u >> 16) & 1u)) >> 16;
  return (ushort)r;
}
__device__ __forceinline__ float bf2f(ushort u) {
  return __uint_as_float((unsigned int)u << 16);
}

__global__ void zero_kernel(float* p, int n) {
  int i = blockIdx.x * 256 + threadIdx.x;
  if (i < n) p[i] = 0.f;
}

__global__ void f2bf_kernel(const float* __restrict__ in, ushort* __restrict__ out, int n) {
  int i = blockIdx.x * 256 + threadIdx.x;
  if (i < n) out[i] = f2bf(in[i]);
}

// WHT latent rows (n<1024): out[n][k] = src[k][c(n)] with
// q=(n>>4)&3 selecting pm/pl/qm/ql, s=((n>>6)<<4)|(n&15).
__global__ void build_wht_latent(const float* __restrict__ prior_w,
                                 const float* __restrict__ post_w,
                                 ushort* __restrict__ out) {
  __shared__ float tile[32][33];
  int k0 = blockIdx.x * 32, n0 = blockIdx.y * 32;
  int tx = threadIdx.x & 31, ty = threadIdx.x >> 5;  // ty 0..7
  int n = n0 + tx;
  int q = (n >> 4) & 3;
  int s = ((n >> 6) << 4) | (n & 15);
  const float* src = (q < 2) ? prior_w : post_w;
  int col = (q & 1) ? (256 + s) : s;
#pragma unroll
  for (int p = 0; p < 4; ++p)
    tile[ty + p * 8][tx] = src[(size_t)(k0 + ty + p * 8) * 512 + col];
  __syncthreads();
#pragma unroll
  for (int p = 0; p < 4; ++p)
    out[(size_t)(n0 + ty + p * 8) * 1024 + k0 + tx] = f2bf(tile[tx][ty + p * 8]);
}

// out[c*ldo + r] = bf16(in[r*ldi + c]); grid (C/32, R/32)
__global__ void trans_conv(const float* __restrict__ in, ushort* __restrict__ out,
                           int ldi, int ldo) {
  __shared__ float tile[32][33];
  int r0 = blockIdx.y * 32, c0 = blockIdx.x * 32;
  int tx = threadIdx.x & 31, ty = threadIdx.x >> 5;
#pragma unroll
  for (int p = 0; p < 4; ++p)
    tile[ty + p * 8][tx] = in[(size_t)(r0 + ty + p * 8) * ldi + c0 + tx];
  __syncthreads();
#pragma unroll
  for (int p = 0; p < 4; ++p)
    out[(size_t)(c0 + ty + p * 8) * ldo + r0 + tx] = f2bf(tile[tx][ty + p * 8]);
}

__global__ void build_bdr(const float* __restrict__ dec_b1, const float* __restrict__ rew_b1,
                          float* __restrict__ bdr) {
  int i = blockIdx.x * 256 + threadIdx.x;  // 2048
  bdr[i] = (i < 1024) ? dec_b1[i] : rew_b1[i - 1024];
}

// ---------------------------------------------------------------------------
// 64x64-tile GEMM (R6 body) — kept for the posterior GEMM (N=512, 9 disp).
// ---------------------------------------------------------------------------
template <int EPI, bool AF32>
__global__ __launch_bounds__(256) void gemm_bf16(
    const void* __restrict__ Av, const ushort* __restrict__ BT,
    const float* __restrict__ bias, void* __restrict__ Cv,
    int K, int lda, int ldb, int ldc) {
  __shared__ __align__(16) ushort As[2][64 * 40];
  __shared__ __align__(16) ushort Bs[2][64 * 40];
  int tid = threadIdx.x;
  int wave = tid >> 6, lane = tid & 63;
  int quad = lane >> 4, l15 = lane & 15;
  int m0 = blockIdx.y * 64, n0 = blockIdx.x * 64;
  int sr = tid >> 2, sc = (tid & 3) * 8;
  const ushort* agb = (const ushort*)Av + (size_t)(m0 + sr) * lda + sc;
  const float*  agf = (const float*)Av + (size_t)(m0 + sr) * lda + sc;
  const ushort* bgp = BT + (size_t)(n0 + sr) * ldb + sc;
  int4 pa0, pa1, pb;
  if (AF32) { pa0 = *(const int4*)agf; pa1 = *(const int4*)(agf + 4); }
  else      { pa0 = *(const int4*)agb; }
  pb = *(const int4*)bgp;
  f32x4 acc[4] = {};
  int buf = 0;
  for (int k0 = 0; k0 < K; k0 += 32, buf ^= 1) {
    int4 st;
    if (AF32) {
      float f[8];
      *(int4*)&f[0] = pa0; *(int4*)&f[4] = pa1;
      ushort u[8];
#pragma unroll
      for (int i = 0; i < 8; ++i) u[i] = f2bf(f[i]);
      st = *(const int4*)u;
    } else {
      st = pa0;
    }
    *(int4*)&As[buf][sr * 40 + sc] = st;
    *(int4*)&Bs[buf][sr * 40 + sc] = pb;
    __syncthreads();
    int kn = k0 + 32;
    if (kn < K) {
      if (AF32) { pa0 = *(const int4*)(agf + kn); pa1 = *(const int4*)(agf + kn + 4); }
      else      { pa0 = *(const int4*)(agb + kn); }
      pb = *(const int4*)(bgp + kn);
    }
    short8 a = *(const short8*)&As[buf][(wave * 16 + l15) * 40 + quad * 8];
#pragma unroll
    for (int c = 0; c < 4; ++c) {
      short8 b = *(const short8*)&Bs[buf][(c * 16 + l15) * 40 + quad * 8];
      acc[c] = __builtin_amdgcn_mfma_f32_16x16x32_bf16(a, b, acc[c], 0, 0, 0);
    }
  }
#pragma unroll
  for (int c = 0; c < 4; ++c) {
#pragma unroll
    for (int r = 0; r < 4; ++r) {
      size_t row = m0 + wave * 16 + quad * 4 + r;
      int col = n0 + c * 16 + l15;
      float v = acc[c][r] + bias[col];
      if (EPI == 1) v = fmaxf(v, 0.f);
      if (EPI == 1) ((ushort*)Cv)[row * ldc + col] = f2bf(v);
      else ((float*)Cv)[row * ldc + col] = v;
    }
  }
}

// ---------------------------------------------------------------------------
// BMx128-tile GEMM (R11), now with DEPTH-2 register prefetch.
//   BM=64 : waves 1x4, wave tile 64x32 (NT=2)
//   BM=128: waves 2x2, wave tile 64x64 (NT=4)
// ---------------------------------------------------------------------------
template <int BM, int EPI, bool AF32>
__global__ __launch_bounds__(256) void gemm_big(
    const void* __restrict__ Av, const ushort* __restrict__ BT,
    const float* __restrict__ bias, void* __restrict__ Cv,
    int K, int lda, int ldb, int ldc) {
  constexpr int BN = 128;
  constexpr int WM = BM / 64;         // 1 or 2
  constexpr int WN = 4 / WM;          // 4 or 2
  constexpr int NT = BN / WN / 16;    // 2 or 4
  __shared__ __align__(16) ushort As[2][BM * 40];
  __shared__ __align__(16) ushort Bs[2][BN * 40];
  int tid = threadIdx.x;
  int w = tid >> 6, lane = tid & 63;
  int quad = lane >> 4, l15 = lane & 15;
  int wm = (WM == 1) ? 0 : (w >> 1);
  int wn = (WM == 1) ? w : (w & 1);
  int m0 = blockIdx.y * BM, n0 = blockIdx.x * BN;
  int sar = (BM == 64) ? (tid >> 2) : (tid >> 1);
  int sac = (BM == 64) ? ((tid & 3) * 8) : ((tid & 1) * 16);
  int sbr = tid >> 1, sbc = (tid & 1) * 16;
  const ushort* agb = (const ushort*)Av + (size_t)(m0 + sar) * lda + sac;
  const float*  agf = (const float*)Av + (size_t)(m0 + sar) * lda + sac;
  const ushort* bgp = BT + (size_t)(n0 + sbr) * ldb + sbc;
  int4 pa[2][2], pb[2][2];
#pragma unroll
  for (int s2 = 0; s2 < 2; ++s2) {
    int kk0 = s2 * 32;
    if (AF32)          { pa[s2][0] = *(const int4*)(agf + kk0); pa[s2][1] = *(const int4*)(agf + kk0 + 4); }
    else if (BM == 64) { pa[s2][0] = *(const int4*)(agb + kk0); }
    else               { pa[s2][0] = *(const int4*)(agb + kk0); pa[s2][1] = *(const int4*)(agb + kk0 + 8); }
    pb[s2][0] = *(const int4*)(bgp + kk0); pb[s2][1] = *(const int4*)(bgp + kk0 + 8);
  }
  f32x4 acc[4][NT] = {};
  for (int k0 = 0; k0 < K; k0 += 32) {
    int cur = (k0 >> 5) & 1;
    if (AF32) {
      float f[8];
      *(int4*)&f[0] = pa[cur][0]; *(int4*)&f[4] = pa[cur][1];
      ushort u[8];
#pragma unroll
      for (int i = 0; i < 8; ++i) u[i] = f2bf(f[i]);
      *(int4*)&As[cur][sar * 40 + sac] = *(const int4*)u;
    } else if (BM == 64) {
      *(int4*)&As[cur][sar * 40 + sac] = pa[cur][0];
    } else {
      *(int4*)&As[cur][sar * 40 + sac] = pa[cur][0];
      *(int4*)&As[cur][sar * 40 + sac + 8] = pa[cur][1];
    }
    *(int4*)&Bs[cur][sbr * 40 + sbc] = pb[cur][0];
    *(int4*)&Bs[cur][sbr * 40 + sbc + 8] = pb[cur][1];
    __syncthreads();
    int kf = k0 + 64;
    if (kf < K) {
      if (AF32)          { pa[cur][0] = *(const int4*)(agf + kf); pa[cur][1] = *(const int4*)(agf + kf + 4); }
      else if (BM == 64) { pa[cur][0] = *(const int4*)(agb + kf); }
      else               { pa[cur][0] = *(const int4*)(agb + kf); pa[cur][1] = *(const int4*)(agb + kf + 8); }
      pb[cur][0] = *(const int4*)(bgp + kf); pb[cur][1] = *(const int4*)(bgp + kf + 8);
    }
    short8 af[4], bfr[NT];
#pragma unroll
    for (int mt = 0; mt < 4; ++mt)
      af[mt] = *(const short8*)&As[cur][(wm * 64 + mt * 16 + l15) * 40 + quad * 8];
#pragma unroll
    for (int nt = 0; nt < NT; ++nt)
      bfr[nt] = *(const short8*)&Bs[cur][(wn * (BN / WN) + nt * 16 + l15) * 40 + quad * 8];
#pragma unroll
    for (int mt = 0; mt < 4; ++mt)
#pragma unroll
      for (int nt = 0; nt < NT; ++nt)
        acc[mt][nt] = __builtin_amdgcn_mfma_f32_16x16x32_bf16(af[mt], bfr[nt], acc[mt][nt], 0, 0, 0);
  }
#pragma unroll
  for (int mt = 0; mt < 4; ++mt)
#pragma unroll
    for (int nt = 0; nt < NT; ++nt)
#pragma unroll
      for (int r = 0; r < 4; ++r) {
        size_t row = m0 + wm * 64 + mt * 16 + quad * 4 + r;
        int col = n0 + wn * (BN / WN) + nt * 16 + l15;
        float v = acc[mt][nt][r] + bias[col];
        if (EPI == 1) { v = fmaxf(v, 0.f); ((ushort*)Cv)[row * ldc + col] = f2bf(v); }
        else ((float*)Cv)[row * ldc + col] = v;
      }
}

// ---------------------------------------------------------------------------
// Phase B kernel 1: G = HB @ WHT (M=256, N=4096, K=1024), BK=64, DEPTH-2
// register prefetch (normal cached loads), single barrier/iter.
// blockIdx.x<16 -> latent-permuted cols, fused z/KL epilogue; else gh -> G.
// ---------------------------------------------------------------------------
__global__ __launch_bounds__(256) void step_g_kernel(
    int t, int tt, const ushort* __restrict__ HB, const ushort* __restrict__ WHT,
    const float* __restrict__ prior_b, const float* __restrict__ poste,
    const float* __restrict__ eps, const float* __restrict__ actions,
    float* __restrict__ G, ushort* __restrict__ xbuf,
    ushort* __restrict__ featc, float* __restrict__ acc_kl) {
  __shared__ __align__(16) ushort As[2][64 * 72];
  __shared__ __align__(16) ushort Bs[2][64 * 72];
  int tid = threadIdx.x;
  int wave = tid >> 6, lane = tid & 63;
  int quad = lane >> 4, l15 = lane & 15;
  int m0 = blockIdx.y * 64, n0 = blockIdx.x * 64;
  int sr = tid >> 2, sc = (tid & 3) * 16;
  const ushort* agp = HB + (size_t)(m0 + sr) * 1024 + sc;
  const ushort* bgp = WHT + (size_t)(n0 + sr) * 1024 + sc;
  int4 pa[2][2], pb[2][2];
#pragma unroll
  for (int s2 = 0; s2 < 2; ++s2) {
    pa[s2][0] = *(const int4*)(agp + s2 * 64);
    pa[s2][1] = *(const int4*)(agp + s2 * 64 + 8);
    pb[s2][0] = *(const int4*)(bgp + s2 * 64);
    pb[s2][1] = *(const int4*)(bgp + s2 * 64 + 8);
  }
  f32x4 acc[4] = {};
  for (int k0 = 0; k0 < 1024; k0 += 64) {
    int cur = (k0 >> 6) & 1;
    ushort* as = &As[cur][0];
    ushort* bs = &Bs[cur][0];
    *(int4*)&as[sr * 72 + sc] = pa[cur][0]; *(int4*)&as[sr * 72 + sc + 8] = pa[cur][1];
    *(int4*)&bs[sr * 72 + sc] = pb[cur][0]; *(int4*)&bs[sr * 72 + sc + 8] = pb[cur][1];
    __syncthreads();
    int kf = k0 + 128;
    if (kf < 1024) {
      pa[cur][0] = *(const int4*)(agp + kf); pa[cur][1] = *(const int4*)(agp + kf + 8);
      pb[cur][0] = *(const int4*)(bgp + kf); pb[cur][1] = *(const int4*)(bgp + kf + 8);
    }
#pragma unroll
    for (int kk = 0; kk < 2; ++kk) {
      short8 a = *(const short8*)&as[(wave * 16 + l15) * 72 + kk * 32 + quad * 8];
#pragma unroll
      for (int c = 0; c < 4; ++c) {
        short8 b = *(const short8*)&bs[(c * 16 + l15) * 72 + kk * 32 + quad * 8];
        acc[c] = __builtin_amdgcn_mfma_f32_16x16x32_bf16(a, b, acc[c], 0, 0, 0);
      }
    }
  }
  if (blockIdx.x < 16) {
    int s = (n0 >> 2) + l15;
    float kl_sum = 0.f;
#pragma unroll
    for (int r = 0; r < 4; ++r) {
      int b = m0 + wave * 16 + quad * 4 + r;
      size_t row = (size_t)t * NB + b;
      float pm = acc[0][r] + prior_b[s];
      float pl = acc[1][r] + prior_b[256 + s];
      float qm = acc[2][r] + poste[row * 512 + s];
      float ql = acc[3][r] + poste[row * 512 + 256 + s];
      float e = eps[row * 256 + s];
      float z = qm + e * expf(ql);
      xbuf[b * 288 + s] = f2bf(z);
      featc[(size_t)(tt * NB + b) * 1280 + 1024 + s] = f2bf(z);
      if (s < NACT) xbuf[b * 288 + 256 + s] = f2bf(actions[row * NACT + s]);
      float vq = expf(2.f * ql), vp = expf(2.f * pl);
      float dm = qm - pm;
      kl_sum += pl - ql + (vq + dm * dm) / (vp + 1e-8f) - 1.f;
    }
    for (int off = 32; off > 0; off >>= 1) kl_sum += __shfl_down(kl_sum, off);
    if (lane == 0) atomicAdd(acc_kl, 0.5f * kl_sum);
  } else {
    int ng = n0 - 1024;
#pragma unroll
    for (int c = 0; c < 4; ++c)
#pragma unroll
      for (int r = 0; r < 4; ++r) {
        int b = m0 + wave * 16 + quad * 4 + r;
        G[(size_t)b * 3072 + ng + c * 16 + l15] = acc[c][r];
      }
  }
}

// ---------------------------------------------------------------------------
// Phase B kernel 2: GRU gates + state update. grid (16,8) x 128 thr,
// DEPTH-2 register prefetch, single barrier/iter.
// ---------------------------------------------------------------------------
__global__ __launch_bounds__(128) void gru_step_kernel(
    int t, int tt, const ushort* __restrict__ xbuf, const ushort* __restrict__ wiht,
    const float* __restrict__ G, const float* __restrict__ bih,
    const float* __restrict__ bhh, const unsigned char* __restrict__ dones,
    float* __restrict__ H, ushort* __restrict__ HB, ushort* __restrict__ featc) {
  __shared__ __align__(16) ushort As[2][32 * 40];
  __shared__ __align__(16) ushort Bs[2][3][64 * 40];
  int tid = threadIdx.x;
  int wave = tid >> 6, lane = tid & 63;
  int quad = lane >> 4, l15 = lane & 15;
  int m0 = blockIdx.y * 32, n0 = blockIdx.x * 64;
  int ar = tid >> 2, ac = (tid & 3) * 8;
  int br = tid >> 1, bc = (tid & 1) * 16;
  const ushort* agp = xbuf + (size_t)(m0 + ar) * 288 + ac;
  const ushort* bgp = wiht + (size_t)(n0 + br) * 288 + bc;
  int4 pa[2], pb[2][3][2];
#pragma unroll
  for (int s2 = 0; s2 < 2; ++s2) {
    pa[s2] = *(const int4*)(agp + s2 * 32);
#pragma unroll
    for (int gg = 0; gg < 3; ++gg) {
      pb[s2][gg][0] = *(const int4*)(bgp + (size_t)gg * 1024 * 288 + s2 * 32);
      pb[s2][gg][1] = *(const int4*)(bgp + (size_t)gg * 1024 * 288 + s2 * 32 + 8);
    }
  }
  f32x4 accv[3][4] = {};
  for (int k0 = 0; k0 < 288; k0 += 32) {
    int cur = (k0 >> 5) & 1;
    *(int4*)&As[cur][ar * 40 + ac] = pa[cur];
#pragma unroll
    for (int gg = 0; gg < 3; ++gg) {
      *(int4*)&Bs[cur][gg][br * 40 + bc] = pb[cur][gg][0];
      *(int4*)&Bs[cur][gg][br * 40 + bc + 8] = pb[cur][gg][1];
    }
    __syncthreads();
    int kf = k0 + 64;
    if (kf < 288) {
      pa[cur] = *(const int4*)(agp + kf);
#pragma unroll
      for (int gg = 0; gg < 3; ++gg) {
        pb[cur][gg][0] = *(const int4*)(bgp + (size_t)gg * 1024 * 288 + kf);
        pb[cur][gg][1] = *(const int4*)(bgp + (size_t)gg * 1024 * 288 + kf + 8);
      }
    }
    short8 a = *(const short8*)&As[cur][(wave * 16 + l15) * 40 + quad * 8];
#pragma unroll
    for (int gg = 0; gg < 3; ++gg) {
#pragma unroll
      for (int c = 0; c < 4; ++c) {
        short8 b = *(const short8*)&Bs[cur][gg][(c * 16 + l15) * 40 + quad * 8];
        accv[gg][c] = __builtin_amdgcn_mfma_f32_16x16x32_bf16(a, b, accv[gg][c], 0, 0, 0);
      }
    }
  }
#pragma unroll
  for (int c = 0; c < 4; ++c) {
#pragma unroll
    for (int r = 0; r < 4; ++r) {
      int b_idx = m0 + wave * 16 + quad * 4 + r;
      int j = n0 + c * 16 + l15;
      const float* g = G + (size_t)b_idx * 3072;
      float ir = accv[0][c][r] + bih[j];
      float iz = accv[1][c][r] + bih[1024 + j];
      float in_ = accv[2][c][r] + bih[2048 + j];
      float hr = g[j] + bhh[j];
      float hz = g[1024 + j] + bhh[1024 + j];
      float hn = g[2048 + j] + bhh[2048 + j];
      float rg = 1.f / (1.f + expf(-(ir + hr)));
      float u = 1.f / (1.f + expf(-(iz + hz)));
      float n = tanhf(in_ + rg * hn);
      float hprev = H[b_idx * 1024 + j];
      float hnext = (1.f - u) * n + u * hprev;
      featc[(size_t)(tt * NB + b_idx) * 1280 + j] = f2bf(hnext);
      float mask = 1.f - (float)dones[t * NB + b_idx];
      float hm = hnext * mask;
      H[b_idx * 1024 + j] = hm;
      HB[b_idx * 1024 + j] = f2bf(hm);
    }
  }
}

// ---------------------------------------------------------------------------
// Decoder-out GEMM + fused recon loss, DEPTH-2 prefetch.
// ---------------------------------------------------------------------------
__global__ __launch_bounds__(256) void decobs_loss_kernel(
    const ushort* __restrict__ A, const ushort* __restrict__ BT,
    const float* __restrict__ bias, const float* __restrict__ obs_next_g,
    float* __restrict__ acc) {
  __shared__ __align__(16) ushort As[2][64 * 40];
  __shared__ __align__(16) ushort Bs[2][64 * 40];
  int tid = threadIdx.x;
  int wave = tid >> 6, lane = tid & 63;
  int quad = lane >> 4, l15 = lane & 15;
  int m0 = blockIdx.y * 64, n0 = blockIdx.x * 64;
  int sr = tid >> 2, sc = (tid & 3) * 8;
  const ushort* agp = A + (size_t)(m0 + sr) * 2048 + sc;
  const ushort* bgp = BT + (size_t)(n0 + sr) * 1024 + sc;
  int4 pa[2], pb[2];
#pragma unroll
  for (int s2 = 0; s2 < 2; ++s2) {
    pa[s2] = *(const int4*)(agp + s2 * 32);
    pb[s2] = *(const int4*)(bgp + s2 * 32);
  }
  f32x4 accm[4] = {};
  for (int k0 = 0; k0 < 1024; k0 += 32) {
    int cur = (k0 >> 5) & 1;
    *(int4*)&As[cur][sr * 40 + sc] = pa[cur];
    *(int4*)&Bs[cur][sr * 40 + sc] = pb[cur];
    __syncthreads();
    int kf = k0 + 64;
    if (kf < 1024) {
      pa[cur] = *(const int4*)(agp + kf);
      pb[cur] = *(const int4*)(bgp + kf);
    }
    short8 a = *(const short8*)&As[cur][(wave * 16 + l15) * 40 + quad * 8];
#pragma unroll
    for (int c = 0; c < 4; ++c) {
      short8 b = *(const short8*)&Bs[cur][(c * 16 + l15) * 40 + quad * 8];
      accm[c] = __builtin_amdgcn_mfma_f32_16x16x32_bf16(a, b, accm[c], 0, 0, 0);
    }
  }
  float local = 0.f;
#pragma unroll
  for (int c = 0; c < 4; ++c) {
#pragma unroll
    for (int r = 0; r < 4; ++r) {
      size_t row = m0 + wave * 16 + quad * 4 + r;
      int col = n0 + c * 16 + l15;
      float v = accm[c][r] + bias[col];
      float d = v - obs_next_g[row * 512 + col];
      local += d * d;
    }
  }
  __shared__ float red[256];
  red[tid] = local;
  __syncthreads();
  for (int st = 128; st > 0; st >>= 1) {
    if (tid < st) red[tid] += red[tid + st];
    __syncthreads();
  }
  if (tid == 0) atomicAdd(&acc[0], red[0]);
}

// Reward matvec + loss. R1 = DR1C + 1024 (bf16, row stride 2048).
__global__ __launch_bounds__(256) void rew_loss_kernel(
    const ushort* __restrict__ R1, const float* __restrict__ w2,
    const float* __restrict__ b2, const float* __restrict__ rewards_g,
    float* __restrict__ acc) {
  int wave = threadIdx.x >> 6;
  int lane = threadIdx.x & 63;
  int row = blockIdx.x * 4 + wave;
  const ushort* rp = R1 + (size_t)row * 2048;
  float s = 0.f;
#pragma unroll
  for (int i = 0; i < 16; ++i) s += bf2f(rp[lane + 64 * i]) * w2[lane + 64 * i];
  for (int off = 32; off > 0; off >>= 1) s += __shfl_down(s, off);
  if (lane == 0) {
    float d = s + b2[0] - rewards_g[row];
    atomicAdd(&acc[1], d * d);
  }
}

__global__ void finalize_kernel(const float* __restrict__ acc, float* __restrict__ out) {
  float recon = acc[0] / ((float)NROWS * 512.f);
  float rew = acc[1] / (float)NROWS;
  float kl = acc[2] / (float)NROWS;
  out[0] = recon + rew + kl;
  out[1] = recon;
  out[2] = rew;
  out[3] = kl;
}

}  // namespace

extern "C" void kernel_launch(void* const* d_in, const int* in_sizes, int n_in,
                              void* d_out, int out_size, void* d_ws, size_t ws_size,
                              hipStream_t stream) {
  const float* obs     = (const float*)d_in[0];
  const float* actions = (const float*)d_in[1];
  const float* rewards = (const float*)d_in[2];
  const unsigned char* dones = (const unsigned char*)d_in[3];
  const float* eps     = (const float*)d_in[4];
  const float* enc_w1  = (const float*)d_in[5];
  const float* enc_b1  = (const float*)d_in[6];
  const float* enc_w2  = (const float*)d_in[7];
  const float* enc_b2  = (const float*)d_in[8];
  const float* gru_wih = (const float*)d_in[9];
  const float* gru_whh = (const float*)d_in[10];
  const float* gru_bih = (const float*)d_in[11];
  const float* gru_bhh = (const float*)d_in[12];
  const float* prior_w = (const float*)d_in[13];
  const float* prior_b = (const float*)d_in[14];
  const float* post_w  = (const float*)d_in[15];
  const float* post_b  = (const float*)d_in[16];
  const float* dec_w1  = (const float*)d_in[17];
  const float* dec_b1  = (const float*)d_in[18];
  const float* dec_w2  = (const float*)d_in[19];
  const float* dec_b2  = (const float*)d_in[20];
  const float* rew_w1  = (const float*)d_in[21];
  const float* rew_b1  = (const float*)d_in[22];
  const float* rew_w2  = (const float*)d_in[23];
  const float* rew_b2  = (const float*)d_in[24];
  float* out = (float*)d_out;
  float* ws = (float*)d_ws;

  float*  POSTE = ws + OFF_POSTE;
  ushort* E1C   = (ushort*)(ws + OFF_E1C);
  ushort* EMBC  = (ushort*)(ws + OFF_EMBC);
  ushort* FEATC = (ushort*)(ws + OFF_FEATC);
  ushort* DR1C  = (ushort*)(ws + OFF_DR1C);
  ushort* WHT   = (ushort*)(ws + OFF_WHT);
  ushort* WIHT  = (ushort*)(ws + OFF_WIHT);
  ushort* WDRT  = (ushort*)(ws + OFF_WDRT);
  ushort* E1T   = (ushort*)(ws + OFF_E1T);
  ushort* E2T   = (ushort*)(ws + OFF_E2T);
  ushort* PET   = (ushort*)(ws + OFF_PET);
  ushort* DW2T  = (ushort*)(ws + OFF_DW2T);
  float*  BDR   = ws + OFF_BDR;
  float*  G     = ws + OFF_G;
  float*  H     = ws + OFF_H;
  ushort* HB    = (ushort*)(ws + OFF_HB);
  float*  ACC   = ws + OFF_ACC;
  ushort* XBUF  = (ushort*)(ws + OFF_XBUF);

  // Phase 0: zero H + HB + ACC (contiguous), build bf16 weights.
  {
    int nzero = NB * 1024 + NB * 512 + 16;  // H + HB + ACC
    zero_kernel<<<(nzero + 255) / 256, 256, 0, stream>>>(H, nzero);
  }
  build_wht_latent<<<dim3(32, 32), 256, 0, stream>>>(prior_w, post_w, WHT);
  f2bf_kernel<<<(3072 * 1024) / 256, 256, 0, stream>>>(
      gru_whh, WHT + (size_t)1024 * 1024, 3072 * 1024);
  f2bf_kernel<<<(3072 * 288) / 256, 256, 0, stream>>>(gru_wih, WIHT, 3072 * 288);
  trans_conv<<<dim3(1024 / 32, 1280 / 32), 256, 0, stream>>>(dec_w1, WDRT, 1024, 1280);
  trans_conv<<<dim3(1024 / 32, 1280 / 32), 256, 0, stream>>>(rew_w1, WDRT + (size_t)1024 * 1280, 1024, 1280);
  trans_conv<<<dim3(1024 / 32, 512 / 32), 256, 0, stream>>>(enc_w1, E1T, 1024, 512);
  trans_conv<<<dim3(1024 / 32, 1024 / 32), 256, 0, stream>>>(enc_w2, E2T, 1024, 1024);
  trans_conv<<<dim3(512 / 32, 1024 / 32), 256, 0, stream>>>(post_w + (size_t)1024 * 512, PET, 512, 1024);
  trans_conv<<<dim3(512 / 32, 1024 / 32), 256, 0, stream>>>(dec_w2, DW2T, 512, 1024);
  build_bdr<<<8, 256, 0, stream>>>(dec_b1, rew_b1, BDR);

  // Phase A: encoder + posterior-from-emb, chunked per group.
  for (int g = 0; g < NGRP; ++g) {
    const float* obs_g = obs + (size_t)g * GROWS * 512;
    gemm_big<64, 1, true><<<dim3(1024 / 128, GROWS / 64), 256, 0, stream>>>(
        (const void*)obs_g, E1T, enc_b1, E1C, 512, 512, 512, 1024);
    gemm_big<64, 1, false><<<dim3(1024 / 128, GROWS / 64), 256, 0, stream>>>(
        (const void*)E1C, E2T, enc_b2, EMBC, 1024, 1024, 1024, 1024);
    gemm_bf16<2, false><<<dim3(8, GROWS / 64), 256, 0, stream>>>(
        (const void*)EMBC, PET, post_b, POSTE + (size_t)g * GROWS * 512, 1024, 1024, 1024, 512);
  }

  // Phase B (per-step kernels) + per-group heads.
  float* acckl = ACC + 2;
  for (int g = 0; g < NGRP; ++g) {
    for (int tt = 0; tt < TGRP; ++tt) {
      int t = g * TGRP + tt;
      step_g_kernel<<<dim3(64, 4), 256, 0, stream>>>(
          t, tt, HB, WHT, prior_b, POSTE, eps, actions, G, XBUF, FEATC, acckl);
      gru_step_kernel<<<dim3(16, 8), 128, 0, stream>>>(
          t, tt, XBUF, WIHT, G, gru_bih, gru_bhh, dones, H, HB, FEATC);
    }
    gemm_big<128, 1, false><<<dim3(2048 / 128, GROWS / 128), 256, 0, stream>>>(
        (const void*)FEATC, WDRT, BDR, DR1C, 1280, 1280, 1280, 2048);
    decobs_loss_kernel<<<dim3(8, GROWS / 64), 256, 0, stream>>>(
        DR1C, DW2T, dec_b2, obs + ((size_t)g * TGRP + 1) * NB * 512, ACC);
    rew_loss_kernel<<<GROWS / 4, 256, 0, stream>>>(
        DR1C + 1024, rew_w2, rew_b2, rewards + (size_t)g * TGRP * NB, ACC);
  }

  finalize_kernel<<<1, 1, 0, stream>>>(ACC, out);
}

// Round 9
// 2700.003 us; speedup vs baseline: 2.0108x; 2.0108x over previous
//
#include <hip/hip_runtime.h>
#include <math.h>

// ---------------------------------------------------------------------------
// WorldModel RSSM forward losses — R14 (= R13 resubmitted; container infra
// failure last round, kernel never executed).
// R12 regressed (5429us): depth-2 prefetch arrays pa[cur] with runtime 'cur'
// went to SCRATCH (VGPR 84, gemm_big 67us, 600GB/s of scratch traffic) —
// rule: runtime-indexed register arrays are demoted to local memory.
// This round re-runs the depth-2 experiment with NAMED registers + explicit
// two-phase unrolled loops (all LDS/reg indices compile-time static):
//   * step_g   : K=1024, BK=64, 8 unrolled pairs, named a00..b11.
//   * gemm_big : BK=32, pair=64 (all K call sites % 64 == 0), named regs.
//   * decobs   : K=1024, BK=32, 16 pairs, named regs.
//   * gru_step : proven R11 depth-1 body.
// Barrier structure identical to R12 (1 barrier/phase; compiler drains
// lgkm before s_barrier so buffer reuse is safe — proven absmax 0.0).
// ---------------------------------------------------------------------------

namespace {

typedef unsigned short ushort;
typedef __attribute__((ext_vector_type(8))) short short8;   // 8 bf16 in 4 VGPRs
typedef __attribute__((ext_vector_type(4))) float f32x4;

constexpr int TSTEPS = 63;
constexpr int NB     = 256;
constexpr int NACT   = 32;
constexpr int NROWS  = TSTEPS * NB;   // 16128
constexpr int TGRP   = 7;
constexpr int NGRP   = 9;
constexpr int GROWS  = TGRP * NB;     // 1792 = 28*64

// ---- workspace layout (floats) --------------------------------------------
constexpr size_t OFF_POSTE = 0;                                     // f32 16128x512
constexpr size_t OFF_OBSB  = OFF_POSTE + (size_t)NROWS * 512;       // (unused)
constexpr size_t OFF_E1C   = OFF_OBSB + (size_t)GROWS * 512 / 2;    // u16 1792x1024
constexpr size_t OFF_EMBC  = OFF_E1C + (size_t)GROWS * 1024 / 2;    // u16 1792x1024
constexpr size_t OFF_FEATC = OFF_EMBC + (size_t)GROWS * 1024 / 2;   // u16 1792x1280
constexpr size_t OFF_DR1C  = OFF_FEATC + (size_t)GROWS * 1280 / 2;  // u16 1792x2048
constexpr size_t OFF_WHT   = OFF_DR1C + (size_t)GROWS * 2048 / 2;   // u16 4096x1024
constexpr size_t OFF_WIHT  = OFF_WHT + (size_t)4096 * 1024 / 2;     // u16 3072x288
constexpr size_t OFF_WDRT  = OFF_WIHT + (size_t)3072 * 288 / 2;     // u16 2048x1280
constexpr size_t OFF_E1T   = OFF_WDRT + (size_t)2048 * 1280 / 2;    // u16 1024x512
constexpr size_t OFF_E2T   = OFF_E1T + (size_t)1024 * 512 / 2;      // u16 1024x1024
constexpr size_t OFF_PET   = OFF_E2T + (size_t)1024 * 1024 / 2;     // u16 512x1024
constexpr size_t OFF_DW2T  = OFF_PET + (size_t)512 * 1024 / 2;      // u16 512x1024
constexpr size_t OFF_BDR   = OFF_DW2T + (size_t)512 * 1024 / 2;     // f32 2048
constexpr size_t OFF_G     = OFF_BDR + 2048;                        // f32 256x3072
constexpr size_t OFF_H     = OFF_G + (size_t)NB * 3072;             // f32 256x1024
constexpr size_t OFF_HB    = OFF_H + (size_t)NB * 1024;             // u16 256x1024
constexpr size_t OFF_ACC   = OFF_HB + (size_t)NB * 1024 / 2;        // f32 16
constexpr size_t OFF_XBUF  = OFF_ACC + 16;                          // u16 256x288

__device__ __forceinline__ ushort f2bf(float f) {
  unsigned int u = __float_as_uint(f);
  unsigned int r = (u + 0x7fffu + ((u >> 16) & 1u)) >> 16;
  return (ushort)r;
}
__device__ __forceinline__ float bf2f(ushort u) {
  return __uint_as_float((unsigned int)u << 16);
}

__global__ void zero_kernel(float* p, int n) {
  int i = blockIdx.x * 256 + threadIdx.x;
  if (i < n) p[i] = 0.f;
}

__global__ void f2bf_kernel(const float* __restrict__ in, ushort* __restrict__ out, int n) {
  int i = blockIdx.x * 256 + threadIdx.x;
  if (i < n) out[i] = f2bf(in[i]);
}

// WHT latent rows (n<1024): out[n][k] = src[k][c(n)] with
// q=(n>>4)&3 selecting pm/pl/qm/ql, s=((n>>6)<<4)|(n&15).
__global__ void build_wht_latent(const float* __restrict__ prior_w,
                                 const float* __restrict__ post_w,
                                 ushort* __restrict__ out) {
  __shared__ float tile[32][33];
  int k0 = blockIdx.x * 32, n0 = blockIdx.y * 32;
  int tx = threadIdx.x & 31, ty = threadIdx.x >> 5;  // ty 0..7
  int n = n0 + tx;
  int q = (n >> 4) & 3;
  int s = ((n >> 6) << 4) | (n & 15);
  const float* src = (q < 2) ? prior_w : post_w;
  int col = (q & 1) ? (256 + s) : s;
#pragma unroll
  for (int p = 0; p < 4; ++p)
    tile[ty + p * 8][tx] = src[(size_t)(k0 + ty + p * 8) * 512 + col];
  __syncthreads();
#pragma unroll
  for (int p = 0; p < 4; ++p)
    out[(size_t)(n0 + ty + p * 8) * 1024 + k0 + tx] = f2bf(tile[tx][ty + p * 8]);
}

// out[c*ldo + r] = bf16(in[r*ldi + c]); grid (C/32, R/32)
__global__ void trans_conv(const float* __restrict__ in, ushort* __restrict__ out,
                           int ldi, int ldo) {
  __shared__ float tile[32][33];
  int r0 = blockIdx.y * 32, c0 = blockIdx.x * 32;
  int tx = threadIdx.x & 31, ty = threadIdx.x >> 5;
#pragma unroll
  for (int p = 0; p < 4; ++p)
    tile[ty + p * 8][tx] = in[(size_t)(r0 + ty + p * 8) * ldi + c0 + tx];
  __syncthreads();
#pragma unroll
  for (int p = 0; p < 4; ++p)
    out[(size_t)(c0 + ty + p * 8) * ldo + r0 + tx] = f2bf(tile[tx][ty + p * 8]);
}

__global__ void build_bdr(const float* __restrict__ dec_b1, const float* __restrict__ rew_b1,
                          float* __restrict__ bdr) {
  int i = blockIdx.x * 256 + threadIdx.x;  // 2048
  bdr[i] = (i < 1024) ? dec_b1[i] : rew_b1[i - 1024];
}

// ---------------------------------------------------------------------------
// 64x64-tile GEMM (R6 body) — kept for the posterior GEMM (N=512, 9 disp).
// ---------------------------------------------------------------------------
template <int EPI, bool AF32>
__global__ __launch_bounds__(256) void gemm_bf16(
    const void* __restrict__ Av, const ushort* __restrict__ BT,
    const float* __restrict__ bias, void* __restrict__ Cv,
    int K, int lda, int ldb, int ldc) {
  __shared__ __align__(16) ushort As[2][64 * 40];
  __shared__ __align__(16) ushort Bs[2][64 * 40];
  int tid = threadIdx.x;
  int wave = tid >> 6, lane = tid & 63;
  int quad = lane >> 4, l15 = lane & 15;
  int m0 = blockIdx.y * 64, n0 = blockIdx.x * 64;
  int sr = tid >> 2, sc = (tid & 3) * 8;
  const ushort* agb = (const ushort*)Av + (size_t)(m0 + sr) * lda + sc;
  const float*  agf = (const float*)Av + (size_t)(m0 + sr) * lda + sc;
  const ushort* bgp = BT + (size_t)(n0 + sr) * ldb + sc;
  int4 pa0, pa1, pb;
  if (AF32) { pa0 = *(const int4*)agf; pa1 = *(const int4*)(agf + 4); }
  else      { pa0 = *(const int4*)agb; }
  pb = *(const int4*)bgp;
  f32x4 acc[4] = {};
  int buf = 0;
  for (int k0 = 0; k0 < K; k0 += 32, buf ^= 1) {
    int4 st;
    if (AF32) {
      float f[8];
      *(int4*)&f[0] = pa0; *(int4*)&f[4] = pa1;
      ushort u[8];
#pragma unroll
      for (int i = 0; i < 8; ++i) u[i] = f2bf(f[i]);
      st = *(const int4*)u;
    } else {
      st = pa0;
    }
    *(int4*)&As[buf][sr * 40 + sc] = st;
    *(int4*)&Bs[buf][sr * 40 + sc] = pb;
    __syncthreads();
    int kn = k0 + 32;
    if (kn < K) {
      if (AF32) { pa0 = *(const int4*)(agf + kn); pa1 = *(const int4*)(agf + kn + 4); }
      else      { pa0 = *(const int4*)(agb + kn); }
      pb = *(const int4*)(bgp + kn);
    }
    short8 a = *(const short8*)&As[buf][(wave * 16 + l15) * 40 + quad * 8];
#pragma unroll
    for (int c = 0; c < 4; ++c) {
      short8 b = *(const short8*)&Bs[buf][(c * 16 + l15) * 40 + quad * 8];
      acc[c] = __builtin_amdgcn_mfma_f32_16x16x32_bf16(a, b, acc[c], 0, 0, 0);
    }
  }
#pragma unroll
  for (int c = 0; c < 4; ++c) {
#pragma unroll
    for (int r = 0; r < 4; ++r) {
      size_t row = m0 + wave * 16 + quad * 4 + r;
      int col = n0 + c * 16 + l15;
      float v = acc[c][r] + bias[col];
      if (EPI == 1) v = fmaxf(v, 0.f);
      if (EPI == 1) ((ushort*)Cv)[row * ldc + col] = f2bf(v);
      else ((float*)Cv)[row * ldc + col] = v;
    }
  }
}

// ---------------------------------------------------------------------------
// BMx128-tile GEMM, depth-2 with NAMED registers (no runtime-indexed arrays).
// Two explicit 32-K phases per loop iter (pair = 64; all K call sites %64==0).
//   BM=64 : waves 1x4, wave tile 64x32 (NT=2)
//   BM=128: waves 2x2, wave tile 64x64 (NT=4)
// ---------------------------------------------------------------------------
template <int BM, int EPI, bool AF32>
__global__ __launch_bounds__(256) void gemm_big(
    const void* __restrict__ Av, const ushort* __restrict__ BT,
    const float* __restrict__ bias, void* __restrict__ Cv,
    int K, int lda, int ldb, int ldc) {
  constexpr int BN = 128;
  constexpr int WM = BM / 64;         // 1 or 2
  constexpr int WN = 4 / WM;          // 4 or 2
  constexpr int NT = BN / WN / 16;    // 2 or 4
  __shared__ __align__(16) ushort As[2][BM * 40];
  __shared__ __align__(16) ushort Bs[2][BN * 40];
  int tid = threadIdx.x;
  int w = tid >> 6, lane = tid & 63;
  int quad = lane >> 4, l15 = lane & 15;
  int wm = (WM == 1) ? 0 : (w >> 1);
  int wn = (WM == 1) ? w : (w & 1);
  int m0 = blockIdx.y * BM, n0 = blockIdx.x * BN;
  int sar = (BM == 64) ? (tid >> 2) : (tid >> 1);
  int sac = (BM == 64) ? ((tid & 3) * 8) : ((tid & 1) * 16);
  int sbr = tid >> 1, sbc = (tid & 1) * 16;
  const ushort* agb = (const ushort*)Av + (size_t)(m0 + sar) * lda + sac;
  const float*  agf = (const float*)Av + (size_t)(m0 + sar) * lda + sac;
  const ushort* bgp = BT + (size_t)(n0 + sbr) * ldb + sbc;

#define LDA_(ax, ay, off)                                                      \
  if (AF32)          { ax = *(const int4*)(agf + (off)); ay = *(const int4*)(agf + (off) + 4); } \
  else if (BM == 64) { ax = *(const int4*)(agb + (off)); }                     \
  else               { ax = *(const int4*)(agb + (off)); ay = *(const int4*)(agb + (off) + 8); }
#define LDB_(bx, by, off)                                                      \
  bx = *(const int4*)(bgp + (off)); by = *(const int4*)(bgp + (off) + 8);
#define STA_(bf, ax, ay)                                                       \
  if (AF32) {                                                                  \
    float f_[8]; *(int4*)&f_[0] = ax; *(int4*)&f_[4] = ay;                     \
    ushort u_[8];                                                              \
    _Pragma("unroll") for (int i_ = 0; i_ < 8; ++i_) u_[i_] = f2bf(f_[i_]);    \
    *(int4*)&As[bf][sar * 40 + sac] = *(const int4*)u_;                        \
  } else if (BM == 64) {                                                       \
    *(int4*)&As[bf][sar * 40 + sac] = ax;                                      \
  } else {                                                                     \
    *(int4*)&As[bf][sar * 40 + sac] = ax;                                      \
    *(int4*)&As[bf][sar * 40 + sac + 8] = ay;                                  \
  }
#define STB_(bf, bx, by)                                                       \
  *(int4*)&Bs[bf][sbr * 40 + sbc] = bx;                                        \
  *(int4*)&Bs[bf][sbr * 40 + sbc + 8] = by;
#define MFMA_(bf)                                                              \
  {                                                                            \
    short8 af_[4], bf_[NT];                                                    \
    _Pragma("unroll") for (int mt = 0; mt < 4; ++mt)                           \
      af_[mt] = *(const short8*)&As[bf][(wm * 64 + mt * 16 + l15) * 40 + quad * 8]; \
    _Pragma("unroll") for (int nt = 0; nt < NT; ++nt)                          \
      bf_[nt] = *(const short8*)&Bs[bf][(wn * (BN / WN) + nt * 16 + l15) * 40 + quad * 8]; \
    _Pragma("unroll") for (int mt = 0; mt < 4; ++mt)                           \
      _Pragma("unroll") for (int nt = 0; nt < NT; ++nt)                        \
        acc[mt][nt] = __builtin_amdgcn_mfma_f32_16x16x32_bf16(af_[mt], bf_[nt], acc[mt][nt], 0, 0, 0); \
  }

  int4 a0x, a0y, b0x, b0y;   // buffer-0 prefetch (k ≡ 0 mod 64)
  int4 a1x, a1y, b1x, b1y;   // buffer-1 prefetch (k ≡ 32 mod 64)
  LDA_(a0x, a0y, 0)  LDB_(b0x, b0y, 0)
  LDA_(a1x, a1y, 32) LDB_(b1x, b1y, 32)
  f32x4 acc[4][NT] = {};
  for (int k0 = 0; k0 < K; k0 += 64) {
    // phase 0 (buffer 0)
    STA_(0, a0x, a0y) STB_(0, b0x, b0y)
    __syncthreads();
    if (k0 + 64 < K) { LDA_(a0x, a0y, k0 + 64) LDB_(b0x, b0y, k0 + 64) }
    MFMA_(0)
    // phase 1 (buffer 1)
    STA_(1, a1x, a1y) STB_(1, b1x, b1y)
    __syncthreads();
    if (k0 + 96 < K) { LDA_(a1x, a1y, k0 + 96) LDB_(b1x, b1y, k0 + 96) }
    MFMA_(1)
  }
#undef LDA_
#undef LDB_
#undef STA_
#undef STB_
#undef MFMA_
#pragma unroll
  for (int mt = 0; mt < 4; ++mt)
#pragma unroll
    for (int nt = 0; nt < NT; ++nt)
#pragma unroll
      for (int r = 0; r < 4; ++r) {
        size_t row = m0 + wm * 64 + mt * 16 + quad * 4 + r;
        int col = n0 + wn * (BN / WN) + nt * 16 + l15;
        float v = acc[mt][nt][r] + bias[col];
        if (EPI == 1) { v = fmaxf(v, 0.f); ((ushort*)Cv)[row * ldc + col] = f2bf(v); }
        else ((float*)Cv)[row * ldc + col] = v;
      }
}

// ---------------------------------------------------------------------------
// Phase B kernel 1: G = HB @ WHT (M=256, N=4096, K=1024), BK=64, depth-2
// with NAMED registers, two explicit 64-K phases per iter (pair = 128).
// blockIdx.x<16 -> latent-permuted cols, fused z/KL epilogue; else gh -> G.
// ---------------------------------------------------------------------------
__global__ __launch_bounds__(256) void step_g_kernel(
    int t, int tt, const ushort* __restrict__ HB, const ushort* __restrict__ WHT,
    const float* __restrict__ prior_b, const float* __restrict__ poste,
    const float* __restrict__ eps, const float* __restrict__ actions,
    float* __restrict__ G, ushort* __restrict__ xbuf,
    ushort* __restrict__ featc, float* __restrict__ acc_kl) {
  __shared__ __align__(16) ushort As[2][64 * 72];
  __shared__ __align__(16) ushort Bs[2][64 * 72];
  int tid = threadIdx.x;
  int wave = tid >> 6, lane = tid & 63;
  int quad = lane >> 4, l15 = lane & 15;
  int m0 = blockIdx.y * 64, n0 = blockIdx.x * 64;
  int sr = tid >> 2, sc = (tid & 3) * 16;
  const ushort* agp = HB + (size_t)(m0 + sr) * 1024 + sc;
  const ushort* bgp = WHT + (size_t)(n0 + sr) * 1024 + sc;
  // named prefetch: buffer 0 holds k≡0 mod 128, buffer 1 holds k≡64 mod 128
  int4 a00 = *(const int4*)agp,        a01 = *(const int4*)(agp + 8);
  int4 b00 = *(const int4*)bgp,        b01 = *(const int4*)(bgp + 8);
  int4 a10 = *(const int4*)(agp + 64), a11 = *(const int4*)(agp + 72);
  int4 b10 = *(const int4*)(bgp + 64), b11 = *(const int4*)(bgp + 72);
  f32x4 acc[4] = {};
#pragma unroll
  for (int k0 = 0; k0 < 1024; k0 += 128) {
    // ---- phase 0: buffer 0 (data at k0) ----
    *(int4*)&As[0][sr * 72 + sc] = a00; *(int4*)&As[0][sr * 72 + sc + 8] = a01;
    *(int4*)&Bs[0][sr * 72 + sc] = b00; *(int4*)&Bs[0][sr * 72 + sc + 8] = b01;
    __syncthreads();
    if (k0 + 128 < 1024) {
      a00 = *(const int4*)(agp + k0 + 128); a01 = *(const int4*)(agp + k0 + 136);
      b00 = *(const int4*)(bgp + k0 + 128); b01 = *(const int4*)(bgp + k0 + 136);
    }
#pragma unroll
    for (int kk = 0; kk < 2; ++kk) {
      short8 a = *(const short8*)&As[0][(wave * 16 + l15) * 72 + kk * 32 + quad * 8];
#pragma unroll
      for (int c = 0; c < 4; ++c) {
        short8 b = *(const short8*)&Bs[0][(c * 16 + l15) * 72 + kk * 32 + quad * 8];
        acc[c] = __builtin_amdgcn_mfma_f32_16x16x32_bf16(a, b, acc[c], 0, 0, 0);
      }
    }
    // ---- phase 1: buffer 1 (data at k0+64) ----
    *(int4*)&As[1][sr * 72 + sc] = a10; *(int4*)&As[1][sr * 72 + sc + 8] = a11;
    *(int4*)&Bs[1][sr * 72 + sc] = b10; *(int4*)&Bs[1][sr * 72 + sc + 8] = b11;
    __syncthreads();
    if (k0 + 192 < 1024) {
      a10 = *(const int4*)(agp + k0 + 192); a11 = *(const int4*)(agp + k0 + 200);
      b10 = *(const int4*)(bgp + k0 + 192); b11 = *(const int4*)(bgp + k0 + 200);
    }
#pragma unroll
    for (int kk = 0; kk < 2; ++kk) {
      short8 a = *(const short8*)&As[1][(wave * 16 + l15) * 72 + kk * 32 + quad * 8];
#pragma unroll
      for (int c = 0; c < 4; ++c) {
        short8 b = *(const short8*)&Bs[1][(c * 16 + l15) * 72 + kk * 32 + quad * 8];
        acc[c] = __builtin_amdgcn_mfma_f32_16x16x32_bf16(a, b, acc[c], 0, 0, 0);
      }
    }
  }
  if (blockIdx.x < 16) {
    int s = (n0 >> 2) + l15;
    float kl_sum = 0.f;
#pragma unroll
    for (int r = 0; r < 4; ++r) {
      int b = m0 + wave * 16 + quad * 4 + r;
      size_t row = (size_t)t * NB + b;
      float pm = acc[0][r] + prior_b[s];
      float pl = acc[1][r] + prior_b[256 + s];
      float qm = acc[2][r] + poste[row * 512 + s];
      float ql = acc[3][r] + poste[row * 512 + 256 + s];
      float e = eps[row * 256 + s];
      float z = qm + e * expf(ql);
      xbuf[b * 288 + s] = f2bf(z);
      featc[(size_t)(tt * NB + b) * 1280 + 1024 + s] = f2bf(z);
      if (s < NACT) xbuf[b * 288 + 256 + s] = f2bf(actions[row * NACT + s]);
      float vq = expf(2.f * ql), vp = expf(2.f * pl);
      float dm = qm - pm;
      kl_sum += pl - ql + (vq + dm * dm) / (vp + 1e-8f) - 1.f;
    }
    for (int off = 32; off > 0; off >>= 1) kl_sum += __shfl_down(kl_sum, off);
    if (lane == 0) atomicAdd(acc_kl, 0.5f * kl_sum);
  } else {
    int ng = n0 - 1024;
#pragma unroll
    for (int c = 0; c < 4; ++c)
#pragma unroll
      for (int r = 0; r < 4; ++r) {
        int b = m0 + wave * 16 + quad * 4 + r;
        G[(size_t)b * 3072 + ng + c * 16 + l15] = acc[c][r];
      }
  }
}

// ---------------------------------------------------------------------------
// Phase B kernel 2 (R11 depth-1 body, proven): GRU gates + state update.
// grid (16,8) x 128 thr.
// ---------------------------------------------------------------------------
__global__ __launch_bounds__(128) void gru_step_kernel(
    int t, int tt, const ushort* __restrict__ xbuf, const ushort* __restrict__ wiht,
    const float* __restrict__ G, const float* __restrict__ bih,
    const float* __restrict__ bhh, const unsigned char* __restrict__ dones,
    float* __restrict__ H, ushort* __restrict__ HB, ushort* __restrict__ featc) {
  __shared__ __align__(16) ushort As[2][32 * 40];
  __shared__ __align__(16) ushort Bs[2][3][64 * 40];
  int tid = threadIdx.x;
  int wave = tid >> 6, lane = tid & 63;
  int quad = lane >> 4, l15 = lane & 15;
  int m0 = blockIdx.y * 32, n0 = blockIdx.x * 64;
  int ar = tid >> 2, ac = (tid & 3) * 8;
  int br = tid >> 1, bc = (tid & 1) * 16;
  const ushort* agp = xbuf + (size_t)(m0 + ar) * 288 + ac;
  const ushort* bgp = wiht + (size_t)(n0 + br) * 288 + bc;
  int4 pa = *(const int4*)agp;
  int4 pb[3][2];
#pragma unroll
  for (int gg = 0; gg < 3; ++gg) {
    pb[gg][0] = *(const int4*)(bgp + (size_t)gg * 1024 * 288);
    pb[gg][1] = *(const int4*)(bgp + (size_t)gg * 1024 * 288 + 8);
  }
  f32x4 accv[3][4] = {};
  int buf = 0;
  for (int k0 = 0; k0 < 288; k0 += 32, buf ^= 1) {
    *(int4*)&As[buf][ar * 40 + ac] = pa;
#pragma unroll
    for (int gg = 0; gg < 3; ++gg) {
      *(int4*)&Bs[buf][gg][br * 40 + bc] = pb[gg][0];
      *(int4*)&Bs[buf][gg][br * 40 + bc + 8] = pb[gg][1];
    }
    __syncthreads();
    int kn = k0 + 32;
    if (kn < 288) {
      pa = *(const int4*)(agp + kn);
#pragma unroll
      for (int gg = 0; gg < 3; ++gg) {
        pb[gg][0] = *(const int4*)(bgp + (size_t)gg * 1024 * 288 + kn);
        pb[gg][1] = *(const int4*)(bgp + (size_t)gg * 1024 * 288 + kn + 8);
      }
    }
    short8 a = *(const short8*)&As[buf][(wave * 16 + l15) * 40 + quad * 8];
#pragma unroll
    for (int gg = 0; gg < 3; ++gg) {
#pragma unroll
      for (int c = 0; c < 4; ++c) {
        short8 b = *(const short8*)&Bs[buf][gg][(c * 16 + l15) * 40 + quad * 8];
        accv[gg][c] = __builtin_amdgcn_mfma_f32_16x16x32_bf16(a, b, accv[gg][c], 0, 0, 0);
      }
    }
  }
#pragma unroll
  for (int c = 0; c < 4; ++c) {
#pragma unroll
    for (int r = 0; r < 4; ++r) {
      int b_idx = m0 + wave * 16 + quad * 4 + r;
      int j = n0 + c * 16 + l15;
      const float* g = G + (size_t)b_idx * 3072;
      float ir = accv[0][c][r] + bih[j];
      float iz = accv[1][c][r] + bih[1024 + j];
      float in_ = accv[2][c][r] + bih[2048 + j];
      float hr = g[j] + bhh[j];
      float hz = g[1024 + j] + bhh[1024 + j];
      float hn = g[2048 + j] + bhh[2048 + j];
      float rg = 1.f / (1.f + expf(-(ir + hr)));
      float u = 1.f / (1.f + expf(-(iz + hz)));
      float n = tanhf(in_ + rg * hn);
      float hprev = H[b_idx * 1024 + j];
      float hnext = (1.f - u) * n + u * hprev;
      featc[(size_t)(tt * NB + b_idx) * 1280 + j] = f2bf(hnext);
      float mask = 1.f - (float)dones[t * NB + b_idx];
      float hm = hnext * mask;
      H[b_idx * 1024 + j] = hm;
      HB[b_idx * 1024 + j] = f2bf(hm);
    }
  }
}

// ---------------------------------------------------------------------------
// Decoder-out GEMM + fused recon loss, depth-2 with NAMED registers.
// K=1024, BK=32, 16 unrolled pairs.
// ---------------------------------------------------------------------------
__global__ __launch_bounds__(256) void decobs_loss_kernel(
    const ushort* __restrict__ A, const ushort* __restrict__ BT,
    const float* __restrict__ bias, const float* __restrict__ obs_next_g,
    float* __restrict__ acc) {
  __shared__ __align__(16) ushort As[2][64 * 40];
  __shared__ __align__(16) ushort Bs[2][64 * 40];
  int tid = threadIdx.x;
  int wave = tid >> 6, lane = tid & 63;
  int quad = lane >> 4, l15 = lane & 15;
  int m0 = blockIdx.y * 64, n0 = blockIdx.x * 64;
  int sr = tid >> 2, sc = (tid & 3) * 8;
  const ushort* agp = A + (size_t)(m0 + sr) * 2048 + sc;
  const ushort* bgp = BT + (size_t)(n0 + sr) * 1024 + sc;
  int4 pa0 = *(const int4*)agp,        pb0 = *(const int4*)bgp;
  int4 pa1 = *(const int4*)(agp + 32), pb1 = *(const int4*)(bgp + 32);
  f32x4 accm[4] = {};
#pragma unroll
  for (int k0 = 0; k0 < 1024; k0 += 64) {
    // phase 0
    *(int4*)&As[0][sr * 40 + sc] = pa0;
    *(int4*)&Bs[0][sr * 40 + sc] = pb0;
    __syncthreads();
    if (k0 + 64 < 1024) {
      pa0 = *(const int4*)(agp + k0 + 64);
      pb0 = *(const int4*)(bgp + k0 + 64);
    }
    {
      short8 a = *(const short8*)&As[0][(wave * 16 + l15) * 40 + quad * 8];
#pragma unroll
      for (int c = 0; c < 4; ++c) {
        short8 b = *(const short8*)&Bs[0][(c * 16 + l15) * 40 + quad * 8];
        accm[c] = __builtin_amdgcn_mfma_f32_16x16x32_bf16(a, b, accm[c], 0, 0, 0);
      }
    }
    // phase 1
    *(int4*)&As[1][sr * 40 + sc] = pa1;
    *(int4*)&Bs[1][sr * 40 + sc] = pb1;
    __syncthreads();
    if (k0 + 96 < 1024) {
      pa1 = *(const int4*)(agp + k0 + 96);
      pb1 = *(const int4*)(bgp + k0 + 96);
    }
    {
      short8 a = *(const short8*)&As[1][(wave * 16 + l15) * 40 + quad * 8];
#pragma unroll
      for (int c = 0; c < 4; ++c) {
        short8 b = *(const short8*)&Bs[1][(c * 16 + l15) * 40 + quad * 8];
        accm[c] = __builtin_amdgcn_mfma_f32_16x16x32_bf16(a, b, accm[c], 0, 0, 0);
      }
    }
  }
  float local = 0.f;
#pragma unroll
  for (int c = 0; c < 4; ++c) {
#pragma unroll
    for (int r = 0; r < 4; ++r) {
      size_t row = m0 + wave * 16 + quad * 4 + r;
      int col = n0 + c * 16 + l15;
      float v = accm[c][r] + bias[col];
      float d = v - obs_next_g[row * 512 + col];
      local += d * d;
    }
  }
  __shared__ float red[256];
  red[tid] = local;
  __syncthreads();
  for (int st = 128; st > 0; st >>= 1) {
    if (tid < st) red[tid] += red[tid + st];
    __syncthreads();
  }
  if (tid == 0) atomicAdd(&acc[0], red[0]);
}

// Reward matvec + loss. R1 = DR1C + 1024 (bf16, row stride 2048).
__global__ __launch_bounds__(256) void rew_loss_kernel(
    const ushort* __restrict__ R1, const float* __restrict__ w2,
    const float* __restrict__ b2, const float* __restrict__ rewards_g,
    float* __restrict__ acc) {
  int wave = threadIdx.x >> 6;
  int lane = threadIdx.x & 63;
  int row = blockIdx.x * 4 + wave;
  const ushort* rp = R1 + (size_t)row * 2048;
  float s = 0.f;
#pragma unroll
  for (int i = 0; i < 16; ++i) s += bf2f(rp[lane + 64 * i]) * w2[lane + 64 * i];
  for (int off = 32; off > 0; off >>= 1) s += __shfl_down(s, off);
  if (lane == 0) {
    float d = s + b2[0] - rewards_g[row];
    atomicAdd(&acc[1], d * d);
  }
}

__global__ void finalize_kernel(const float* __restrict__ acc, float* __restrict__ out) {
  float recon = acc[0] / ((float)NROWS * 512.f);
  float rew = acc[1] / (float)NROWS;
  float kl = acc[2] / (float)NROWS;
  out[0] = recon + rew + kl;
  out[1] = recon;
  out[2] = rew;
  out[3] = kl;
}

}  // namespace

extern "C" void kernel_launch(void* const* d_in, const int* in_sizes, int n_in,
                              void* d_out, int out_size, void* d_ws, size_t ws_size,
                              hipStream_t stream) {
  const float* obs     = (const float*)d_in[0];
  const float* actions = (const float*)d_in[1];
  const float* rewards = (const float*)d_in[2];
  const unsigned char* dones = (const unsigned char*)d_in[3];
  const float* eps     = (const float*)d_in[4];
  const float* enc_w1  = (const float*)d_in[5];
  const float* enc_b1  = (const float*)d_in[6];
  const float* enc_w2  = (const float*)d_in[7];
  const float* enc_b2  = (const float*)d_in[8];
  const float* gru_wih = (const float*)d_in[9];
  const float* gru_whh = (const float*)d_in[10];
  const float* gru_bih = (const float*)d_in[11];
  const float* gru_bhh = (const float*)d_in[12];
  const float* prior_w = (const float*)d_in[13];
  const float* prior_b = (const float*)d_in[14];
  const float* post_w  = (const float*)d_in[15];
  const float* post_b  = (const float*)d_in[16];
  const float* dec_w1  = (const float*)d_in[17];
  const float* dec_b1  = (const float*)d_in[18];
  const float* dec_w2  = (const float*)d_in[19];
  const float* dec_b2  = (const float*)d_in[20];
  const float* rew_w1  = (const float*)d_in[21];
  const float* rew_b1  = (const float*)d_in[22];
  const float* rew_w2  = (const float*)d_in[23];
  const float* rew_b2  = (const float*)d_in[24];
  float* out = (float*)d_out;
  float* ws = (float*)d_ws;

  float*  POSTE = ws + OFF_POSTE;
  ushort* E1C   = (ushort*)(ws + OFF_E1C);
  ushort* EMBC  = (ushort*)(ws + OFF_EMBC);
  ushort* FEATC = (ushort*)(ws + OFF_FEATC);
  ushort* DR1C  = (ushort*)(ws + OFF_DR1C);
  ushort* WHT   = (ushort*)(ws + OFF_WHT);
  ushort* WIHT  = (ushort*)(ws + OFF_WIHT);
  ushort* WDRT  = (ushort*)(ws + OFF_WDRT);
  ushort* E1T   = (ushort*)(ws + OFF_E1T);
  ushort* E2T   = (ushort*)(ws + OFF_E2T);
  ushort* PET   = (ushort*)(ws + OFF_PET);
  ushort* DW2T  = (ushort*)(ws + OFF_DW2T);
  float*  BDR   = ws + OFF_BDR;
  float*  G     = ws + OFF_G;
  float*  H     = ws + OFF_H;
  ushort* HB    = (ushort*)(ws + OFF_HB);
  float*  ACC   = ws + OFF_ACC;
  ushort* XBUF  = (ushort*)(ws + OFF_XBUF);

  // Phase 0: zero H + HB + ACC (contiguous), build bf16 weights.
  {
    int nzero = NB * 1024 + NB * 512 + 16;  // H + HB + ACC
    zero_kernel<<<(nzero + 255) / 256, 256, 0, stream>>>(H, nzero);
  }
  build_wht_latent<<<dim3(32, 32), 256, 0, stream>>>(prior_w, post_w, WHT);
  f2bf_kernel<<<(3072 * 1024) / 256, 256, 0, stream>>>(
      gru_whh, WHT + (size_t)1024 * 1024, 3072 * 1024);
  f2bf_kernel<<<(3072 * 288) / 256, 256, 0, stream>>>(gru_wih, WIHT, 3072 * 288);
  trans_conv<<<dim3(1024 / 32, 1280 / 32), 256, 0, stream>>>(dec_w1, WDRT, 1024, 1280);
  trans_conv<<<dim3(1024 / 32, 1280 / 32), 256, 0, stream>>>(rew_w1, WDRT + (size_t)1024 * 1280, 1024, 1280);
  trans_conv<<<dim3(1024 / 32, 512 / 32), 256, 0, stream>>>(enc_w1, E1T, 1024, 512);
  trans_conv<<<dim3(1024 / 32, 1024 / 32), 256, 0, stream>>>(enc_w2, E2T, 1024, 1024);
  trans_conv<<<dim3(512 / 32, 1024 / 32), 256, 0, stream>>>(post_w + (size_t)1024 * 512, PET, 512, 1024);
  trans_conv<<<dim3(512 / 32, 1024 / 32), 256, 0, stream>>>(dec_w2, DW2T, 512, 1024);
  build_bdr<<<8, 256, 0, stream>>>(dec_b1, rew_b1, BDR);

  // Phase A: encoder + posterior-from-emb, chunked per group.
  for (int g = 0; g < NGRP; ++g) {
    const float* obs_g = obs + (size_t)g * GROWS * 512;
    gemm_big<64, 1, true><<<dim3(1024 / 128, GROWS / 64), 256, 0, stream>>>(
        (const void*)obs_g, E1T, enc_b1, E1C, 512, 512, 512, 1024);
    gemm_big<64, 1, false><<<dim3(1024 / 128, GROWS / 64), 256, 0, stream>>>(
        (const void*)E1C, E2T, enc_b2, EMBC, 1024, 1024, 1024, 1024);
    gemm_bf16<2, false><<<dim3(8, GROWS / 64), 256, 0, stream>>>(
        (const void*)EMBC, PET, post_b, POSTE + (size_t)g * GROWS * 512, 1024, 1024, 1024, 512);
  }

  // Phase B (per-step kernels) + per-group heads.
  float* acckl = ACC + 2;
  for (int g = 0; g < NGRP; ++g) {
    for (int tt = 0; tt < TGRP; ++tt) {
      int t = g * TGRP + tt;
      step_g_kernel<<<dim3(64, 4), 256, 0, stream>>>(
          t, tt, HB, WHT, prior_b, POSTE, eps, actions, G, XBUF, FEATC, acckl);
      gru_step_kernel<<<dim3(16, 8), 128, 0, stream>>>(
          t, tt, XBUF, WIHT, G, gru_bih, gru_bhh, dones, H, HB, FEATC);
    }
    gemm_big<128, 1, false><<<dim3(2048 / 128, GROWS / 128), 256, 0, stream>>>(
        (const void*)FEATC, WDRT, BDR, DR1C, 1280, 1280, 1280, 2048);
    decobs_loss_kernel<<<dim3(8, GROWS / 64), 256, 0, stream>>>(
        DR1C, DW2T, dec_b2, obs + ((size_t)g * TGRP + 1) * NB * 512, ACC);
    rew_loss_kernel<<<GROWS / 4, 256, 0, stream>>>(
        DR1C + 1024, rew_w2, rew_b2, rewards + (size_t)g * TGRP * NB, ACC);
  }

  finalize_kernel<<<1, 1, 0, stream>>>(ACC, out);
}